// Round 2
// baseline (236.000 us; speedup 1.0000x reference)
//
#include <hip/hip_runtime.h>
#include <hip/hip_bf16.h>

// Problem constants: BS=8, H=16, NUM_JOB=64, OPS_PER_JOB=32, DK=64, L=2048.
// Model reduces to 8192 independent causal-attention problems of 32 tok x 64
// dim with RoPE positions 0..31 reset per job. Output dtype: float32.
//
// R3: chip-wide phase-overlap pass. R2 post-mortem showed per-wave V-load
// placement is not first-order (compiler sank the prefetch; R0 with fully
// exposed V latency was no slower). Everything idle (MfmaUtil 0.7%, VALU 11%,
// HBM 22%) + grid == exactly one wave generation => all 8192 waves march in
// lockstep through {QK-read burst 134MB -> compute -> V burst 67MB -> store
// burst 67MB}; phases serialize on the memory system (~90us at ~2.8TB/s).
// Fix: 4 jobs per wave, software-pipelined (issue QK(t+1) before job t's
// compute, V(t+1) after V(t) consumed), so stores of job t overlap loads of
// job t+1 chip-wide. Issue order pinned with sched_barrier(0). RoPE tables
// hoisted (positions identical across jobs). Stores nontemporal (stop output
// evicting the 201MB input from 256MB L3; FETCH was 98MB).

typedef _Float16 h8 __attribute__((ext_vector_type(8)));
typedef float f4 __attribute__((ext_vector_type(4)));
typedef unsigned short us8 __attribute__((ext_vector_type(8)));

// ln(10000)/32: theta_i = exp(-i * this)
#define ROPE_LN_CONST 0.28782313662425575f

__device__ __forceinline__ float bf2f(unsigned short u) {
    return __uint_as_float(((unsigned int)u) << 16);
}

template<bool ISBF>
__device__ __forceinline__ void run(
    const void* __restrict__ qp, const void* __restrict__ kp,
    const void* __restrict__ vp, float* __restrict__ outp,
    _Float16* __restrict__ myps,
    const int lg, const int ln, const int b, const int h, const int j0)
{
    const size_t base0 = ((size_t)((b * 16 + h) * 2048 + j0 * 32)) * 64;

    // ---- hoisted RoPE tables: identical for all 4 jobs (pos resets per job).
    float csT[2][2][4], snT[2][2][4];
#pragma unroll
    for (int ti = 0; ti < 2; ++ti) {
        const float r = (float)(ti * 16 + ln);
#pragma unroll
        for (int c = 0; c < 2; ++c) {
#pragma unroll
            for (int t2 = 0; t2 < 4; ++t2) {
                const int i = ((c * 32 + lg * 8) >> 1) + t2;  // pair index 0..31
                const float th = __expf(-(float)i * ROPE_LN_CONST);
                __sincosf(r * th, &snT[ti][c][t2], &csT[ti][c][t2]);
            }
        }
    }

    // Raw staging registers (issue-early / convert-late so prefetch survives).
    us8 qrb[2][2], krb[2][2];        // bf16 raw
    f4  qrf[2][2][2], krf[2][2][2];  // f32 raw
    unsigned int vr[32];             // V raw words (single buffer)
    h8 qf[2][2], kf[2][2];           // current job's RoPE'd f16 frags

    // A-frag addressing: lane holds M[row = ti*16+ln][k = lg*8+t], chunks c*32.
    auto issueQK = [&](size_t base) {
#pragma unroll
        for (int ti = 0; ti < 2; ++ti) {
            const size_t roff = base + (size_t)(ti * 16 + ln) * 64;
#pragma unroll
            for (int c = 0; c < 2; ++c) {
                const size_t off = roff + c * 32 + lg * 8;
                if constexpr (ISBF) {
                    qrb[ti][c] = *(const us8*)((const unsigned short*)qp + off);
                    krb[ti][c] = *(const us8*)((const unsigned short*)kp + off);
                } else {
                    const float* q = (const float*)qp + off;
                    const float* k = (const float*)kp + off;
                    qrf[ti][c][0] = *(const f4*)q;
                    qrf[ti][c][1] = *(const f4*)(q + 4);
                    krf[ti][c][0] = *(const f4*)k;
                    krf[ti][c][1] = *(const f4*)(k + 4);
                }
            }
        }
    };

    // B-frag: vf[tj][t] = V[p = lg*8+t][d = tj*16+ln]
    auto issueV = [&](size_t base) {
#pragma unroll
        for (int tj = 0; tj < 4; ++tj)
#pragma unroll
            for (int t2 = 0; t2 < 8; ++t2) {
                const size_t off = base + (size_t)(lg * 8 + t2) * 64 + tj * 16 + ln;
                if constexpr (ISBF)
                    vr[tj * 8 + t2] = ((const unsigned short*)vp)[off];
                else
                    vr[tj * 8 + t2] = ((const unsigned int*)vp)[off];
            }
    };

    auto ropeQK = [&]() {
#pragma unroll
        for (int ti = 0; ti < 2; ++ti)
#pragma unroll
            for (int c = 0; c < 2; ++c) {
                float qa[8], ka[8];
                if constexpr (ISBF) {
#pragma unroll
                    for (int t2 = 0; t2 < 8; ++t2) {
                        qa[t2] = bf2f(qrb[ti][c][t2]);
                        ka[t2] = bf2f(krb[ti][c][t2]);
                    }
                } else {
#pragma unroll
                    for (int t2 = 0; t2 < 8; ++t2) {
                        qa[t2] = qrf[ti][c][t2 >> 2][t2 & 3];
                        ka[t2] = krf[ti][c][t2 >> 2][t2 & 3];
                    }
                }
#pragma unroll
                for (int t2 = 0; t2 < 4; ++t2) {
                    const float cs = csT[ti][c][t2], sn = snT[ti][c][t2];
                    const float qe = qa[2 * t2], qo = qa[2 * t2 + 1];
                    const float ke = ka[2 * t2], ko = ka[2 * t2 + 1];
                    qf[ti][c][2 * t2]     = (_Float16)(qe * cs - qo * sn);
                    qf[ti][c][2 * t2 + 1] = (_Float16)(qo * cs + qe * sn);
                    kf[ti][c][2 * t2]     = (_Float16)(ke * cs - ko * sn);
                    kf[ti][c][2 * t2 + 1] = (_Float16)(ko * cs + ke * sn);
                }
            }
    };

    // ---- prologue: job 0 in flight ----
    issueQK(base0);
    issueV(base0);
    __builtin_amdgcn_sched_barrier(0);
    ropeQK();   // waits QK(0); V(0) stays in flight behind it

#pragma unroll
    for (int t = 0; t < 4; ++t) {
        const size_t basen = base0 + (size_t)(t + 1) * 2048;  // next job, 32*64 elems

        // -- issue next job's Q/K while this job computes --
        if (t < 3) issueQK(basen);
        __builtin_amdgcn_sched_barrier(0);

        // ---- S = Qr * Kr^T : 2x2 tiles of 16x16, K=64 in two chunks ----
        f4 sacc[2][2];
#pragma unroll
        for (int ti = 0; ti < 2; ++ti)
#pragma unroll
            for (int tj = 0; tj < 2; ++tj) {
                f4 acc = {0.f, 0.f, 0.f, 0.f};
                acc = __builtin_amdgcn_mfma_f32_16x16x32_f16(qf[ti][0], kf[tj][0], acc, 0, 0, 0);
                acc = __builtin_amdgcn_mfma_f32_16x16x32_f16(qf[ti][1], kf[tj][1], acc, 0, 0, 0);
                sacc[ti][tj] = acc;
            }

        // ---- causal softmax in C/D layout: row = ti*16+lg*4+reg, col = tj*16+ln ----
#pragma unroll
        for (int ti = 0; ti < 2; ++ti) {
#pragma unroll
            for (int reg = 0; reg < 4; ++reg) {
                const int row = ti * 16 + lg * 4 + reg;
                float s0 = sacc[ti][0][reg] * 0.125f;      // 1/sqrt(64)
                float s1 = sacc[ti][1][reg] * 0.125f;
                if (ln > row)      s0 = -INFINITY;
                if (16 + ln > row) s1 = -INFINITY;
                float m = fmaxf(s0, s1);
#pragma unroll
                for (int off = 8; off > 0; off >>= 1) m = fmaxf(m, __shfl_xor(m, off, 64));
                float p0 = __expf(s0 - m);                 // exp(-inf)=0 handles mask
                float p1 = __expf(s1 - m);
                float l = p0 + p1;
#pragma unroll
                for (int off = 8; off > 0; off >>= 1) l += __shfl_xor(l, off, 64);
                const float linv = 1.0f / l;
                sacc[ti][0][reg] = p0 * linv;              // fold 1/l into P
                sacc[ti][1][reg] = p1 * linv;
            }
        }

        // ---- transpose P: C/D layout -> A layout via wave-private LDS (f16) ----
#pragma unroll
        for (int ti = 0; ti < 2; ++ti)
#pragma unroll
            for (int tj = 0; tj < 2; ++tj)
#pragma unroll
                for (int reg = 0; reg < 4; ++reg)
                    myps[(ti * 16 + lg * 4 + reg) * 40 + tj * 16 + ln] =
                        (_Float16)sacc[ti][tj][reg];

        // Wave-private buffer: only wave-local ordering needed, no barrier.
        asm volatile("s_waitcnt lgkmcnt(0)" ::: "memory");
        __builtin_amdgcn_sched_barrier(0);

        // A-frag read: row = ti*16+ln, k contiguous -> one b128 per tile.
        h8 paf[2];
#pragma unroll
        for (int ti = 0; ti < 2; ++ti)
            paf[ti] = *(const h8*)&myps[(ti * 16 + ln) * 40 + lg * 8];

        // ---- consume V(t) (vm-wait lands here; covered by QK/softmax above) ----
        h8 vf[4];
#pragma unroll
        for (int tj = 0; tj < 4; ++tj)
#pragma unroll
            for (int t2 = 0; t2 < 8; ++t2)
                vf[tj][t2] = ISBF
                    ? (_Float16)bf2f((unsigned short)vr[tj * 8 + t2])
                    : (_Float16)__uint_as_float(vr[tj * 8 + t2]);

        // -- vr free: issue next job's V; covered until next body's consume --
        if (t < 3) issueV(basen);
        __builtin_amdgcn_sched_barrier(0);

        // ---- O = P * V, store fused, nontemporal (output never re-read;
        // keep the 201MB input resident in L3) ----
#pragma unroll
        for (int ti = 0; ti < 2; ++ti) {
#pragma unroll
            for (int tj = 0; tj < 4; ++tj) {
                f4 acc = {0.f, 0.f, 0.f, 0.f};
                acc = __builtin_amdgcn_mfma_f32_16x16x32_f16(paf[ti], vf[tj], acc, 0, 0, 0);
#pragma unroll
                for (int reg = 0; reg < 4; ++reg) {
                    const int row = ti * 16 + lg * 4 + reg;
                    __builtin_nontemporal_store(acc[reg],
                        &outp[((size_t)b * 2048 + (j0 + t) * 32 + row) * 1024
                              + h * 64 + tj * 16 + ln]);
                }
            }
        }

        // ---- RoPE next job's Q/K (waits QK(t+1); V(t+1) stays behind) ----
        if (t < 3) ropeQK();
    }
}

__global__ __launch_bounds__(256, 2)
void attn_jobs(const void* __restrict__ qp, const void* __restrict__ kp,
               const void* __restrict__ vp, float* __restrict__ outp) {
    // Per-wave P-transpose buffer, f16, row stride 40 (16B-aligned rows,
    // <=2-way bank aliasing on the b128 reads).
    __shared__ alignas(16) _Float16 ps[4][32 * 40];

    const int tid  = threadIdx.x;
    const int wid  = tid >> 6;
    const int lane = tid & 63;
    const int lg   = lane >> 4;
    const int ln   = lane & 15;

    const int w  = blockIdx.x * 4 + wid;  // wave id, 0..2047
    const int g  = w * 4;                 // first of 4 consecutive jobs
    const int j0 = g & 63;                // j0..j0+3 share (b,h)
    const int h  = (g >> 6) & 15;
    const int b  = g >> 10;

    // ---- input dtype probe (wave-uniform): bf16 stream has bf16-exponent at
    // bits[14:7] of every dword; f32 stream has uniform mantissa bits there.
    unsigned int w0 = ((const unsigned int*)qp)[lane];
    unsigned int e8 = (w0 >> 7) & 0xFFu;
    bool hitb = (e8 >= 96u) && (e8 <= 144u);
    const bool isbf = (__popcll(__ballot(hitb)) >= 32);

    if (isbf) run<true >(qp, kp, vp, outp, ps[wid], lg, ln, b, h, j0);
    else      run<false>(qp, kp, vp, outp, ps[wid], lg, ln, b, h, j0);
}

extern "C" void kernel_launch(void* const* d_in, const int* in_sizes, int n_in,
                              void* d_out, int out_size, void* d_ws, size_t ws_size,
                              hipStream_t stream) {
    (void)in_sizes; (void)n_in; (void)d_ws; (void)ws_size; (void)out_size;
    const void* q = d_in[0];
    const void* k = d_in[1];
    const void* v = d_in[2];
    // d_in[3] (op_mapping) / d_in[4] (triu_mask) are deterministic constants;
    // their structure is baked into the kernel.
    attn_jobs<<<512, 256, 0, stream>>>(q, k, v, (float*)d_out);
}

// Round 3
// 223.502 us; speedup vs baseline: 1.0559x; 1.0559x over previous
//
#include <hip/hip_runtime.h>
#include <hip/hip_bf16.h>

// Problem constants: BS=8, H=16, NUM_JOB=64, OPS_PER_JOB=32, DK=64, L=2048.
// Model reduces to 8192 independent causal-attention problems of 32 tok x 64
// dim with RoPE positions 0..31 reset per job. Output dtype: float32.
//
// R4: un-sinkable V prefetch via global_load_lds.
// Post-mortems: R2's register V-prefetch was sunk by the compiler (VGPR 80->60,
// vr[] never live); R3 showed occupancy 17% vs 34% barely matters. Delivered
// BW is stuck at ~3.0 TB/s (268MB/90us) with no pipe saturated => Little's-law
// cap: per-wave in-flight bytes too low, V phase serialized after Q/K phase.
// global_load_lds has NO dest register: the compiler cannot sink it, it costs
// 0 VGPRs, and all of Q+K+V (24KB/wave) goes in flight at the top. V latency
// hides under RoPE + QK-MFMA + softmax. Otherwise back to the best-measured
// R0 shape: 2048 blocks x 256, 1 job/wave, launch_bounds(256,4), plain f32
// stores (R3's nontemporal stores grew WRITE_SIZE 65.5->80MB; reverted).
// P transpose kept f16 @ stride 40 (R2: bank conflicts 8x lower, LDS smaller).

typedef _Float16 h8 __attribute__((ext_vector_type(8)));
typedef float f4 __attribute__((ext_vector_type(4)));
typedef unsigned short us8 __attribute__((ext_vector_type(8)));

// ln(10000)/32: theta_i = exp(-i * this)
#define ROPE_LN_CONST 0.28782313662425575f

__device__ __forceinline__ float bf2f(unsigned short u) {
    return __uint_as_float(((unsigned int)u) << 16);
}

template<bool ISBF>
__device__ __forceinline__ void run(
    const void* __restrict__ qp, const void* __restrict__ kp,
    const void* __restrict__ vp, float* __restrict__ outp,
    _Float16* __restrict__ myps, unsigned char* __restrict__ myv,
    const int lane, const int lg, const int ln,
    const int b, const int h, const int j)
{
    const size_t base = ((size_t)((b * 16 + h) * 2048 + j * 32)) * 64;

    // ---- issue Q/K raw loads (A-frag addressing: lane holds
    // M[row = ti*16+ln][k = lg*8+t], k-chunks c*32) ----
    us8 qrb[2][2], krb[2][2];        // bf16 raw
    f4  qrf[2][2][2], krf[2][2][2];  // f32 raw
#pragma unroll
    for (int ti = 0; ti < 2; ++ti) {
        const size_t roff = base + (size_t)(ti * 16 + ln) * 64;
#pragma unroll
        for (int c = 0; c < 2; ++c) {
            const size_t off = roff + c * 32 + lg * 8;
            if constexpr (ISBF) {
                qrb[ti][c] = *(const us8*)((const unsigned short*)qp + off);
                krb[ti][c] = *(const us8*)((const unsigned short*)kp + off);
            } else {
                const float* q = (const float*)qp + off;
                const float* k = (const float*)kp + off;
                qrf[ti][c][0] = *(const f4*)q;
                qrf[ti][c][1] = *(const f4*)(q + 4);
                krf[ti][c][0] = *(const f4*)k;
                krf[ti][c][1] = *(const f4*)(k + 4);
            }
        }
    }

    // ---- issue V -> LDS (global_load_lds width 16: wave-uniform LDS base +
    // lane*16, per-lane global addr). No dest reg => cannot be sunk; 0 VGPR.
    // LDS layout = linear row-major V[32][64], same as global. ----
    if constexpr (ISBF) {
#pragma unroll
        for (int i = 0; i < 4; ++i)   // 1KB/inst = 8 rows of 128B
            __builtin_amdgcn_global_load_lds(
                (const __attribute__((address_space(1))) void*)
                    ((const unsigned short*)vp + base + i * 512 + lane * 8),
                (__attribute__((address_space(3))) void*)(myv + i * 1024),
                16, 0, 0);
    } else {
#pragma unroll
        for (int i = 0; i < 8; ++i)   // 1KB/inst = 4 rows of 256B
            __builtin_amdgcn_global_load_lds(
                (const __attribute__((address_space(1))) void*)
                    ((const float*)vp + base + i * 256 + lane * 4),
                (__attribute__((address_space(3))) void*)(myv + i * 1024),
                16, 0, 0);
    }
    __builtin_amdgcn_sched_barrier(0);

    // ---- RoPE Q/K -> f16 frags (vmcnt waits cover Q/K only; V glds younger) ----
    h8 qf[2][2], kf[2][2];
#pragma unroll
    for (int ti = 0; ti < 2; ++ti) {
        const float r = (float)(ti * 16 + ln);   // token index = RoPE pos
#pragma unroll
        for (int c = 0; c < 2; ++c) {
            float qa[8], ka[8];
            if constexpr (ISBF) {
#pragma unroll
                for (int t = 0; t < 8; ++t) {
                    qa[t] = bf2f(qrb[ti][c][t]);
                    ka[t] = bf2f(krb[ti][c][t]);
                }
            } else {
#pragma unroll
                for (int t = 0; t < 8; ++t) {
                    qa[t] = qrf[ti][c][t >> 2][t & 3];
                    ka[t] = krf[ti][c][t >> 2][t & 3];
                }
            }
#pragma unroll
            for (int t = 0; t < 4; ++t) {
                const int i = ((c * 32 + lg * 8) >> 1) + t;   // pair idx 0..31
                const float th = __expf(-(float)i * ROPE_LN_CONST);
                float sn, cs;
                __sincosf(r * th, &sn, &cs);
                const float qe = qa[2 * t], qo = qa[2 * t + 1];
                const float ke = ka[2 * t], ko = ka[2 * t + 1];
                qf[ti][c][2 * t]     = (_Float16)(qe * cs - qo * sn);
                qf[ti][c][2 * t + 1] = (_Float16)(qo * cs + qe * sn);
                kf[ti][c][2 * t]     = (_Float16)(ke * cs - ko * sn);
                kf[ti][c][2 * t + 1] = (_Float16)(ko * cs + ke * sn);
            }
        }
    }

    // ---- S = Qr * Kr^T : 2x2 tiles of 16x16, K=64 in two chunks ----
    f4 sacc[2][2];
#pragma unroll
    for (int ti = 0; ti < 2; ++ti)
#pragma unroll
        for (int tj = 0; tj < 2; ++tj) {
            f4 acc = {0.f, 0.f, 0.f, 0.f};
            acc = __builtin_amdgcn_mfma_f32_16x16x32_f16(qf[ti][0], kf[tj][0], acc, 0, 0, 0);
            acc = __builtin_amdgcn_mfma_f32_16x16x32_f16(qf[ti][1], kf[tj][1], acc, 0, 0, 0);
            sacc[ti][tj] = acc;
        }

    // ---- causal softmax in C/D layout: row = ti*16+lg*4+reg, col = tj*16+ln ----
#pragma unroll
    for (int ti = 0; ti < 2; ++ti) {
#pragma unroll
        for (int reg = 0; reg < 4; ++reg) {
            const int row = ti * 16 + lg * 4 + reg;
            float s0 = sacc[ti][0][reg] * 0.125f;       // 1/sqrt(64)
            float s1 = sacc[ti][1][reg] * 0.125f;
            if (ln > row)      s0 = -INFINITY;
            if (16 + ln > row) s1 = -INFINITY;
            float m = fmaxf(s0, s1);
#pragma unroll
            for (int off = 8; off > 0; off >>= 1) m = fmaxf(m, __shfl_xor(m, off, 64));
            float p0 = __expf(s0 - m);                  // exp(-inf)=0 handles mask
            float p1 = __expf(s1 - m);
            float l = p0 + p1;
#pragma unroll
            for (int off = 8; off > 0; off >>= 1) l += __shfl_xor(l, off, 64);
            const float linv = 1.0f / l;
            sacc[ti][0][reg] = p0 * linv;               // fold 1/l into P
            sacc[ti][1][reg] = p1 * linv;
        }
    }

    // ---- transpose P: C/D layout -> A layout via wave-private LDS (f16) ----
#pragma unroll
    for (int ti = 0; ti < 2; ++ti)
#pragma unroll
        for (int tj = 0; tj < 2; ++tj)
#pragma unroll
            for (int reg = 0; reg < 4; ++reg)
                myps[(ti * 16 + lg * 4 + reg) * 40 + tj * 16 + ln] =
                    (_Float16)sacc[ti][tj][reg];

    // Wave-private buffer: wave-local ordering only (no barrier needed).
    asm volatile("s_waitcnt lgkmcnt(0)" ::: "memory");
    __builtin_amdgcn_sched_barrier(0);

    // A-frag read: row = ti*16+ln, k contiguous -> one b128 per tile.
    h8 paf[2];
#pragma unroll
    for (int ti = 0; ti < 2; ++ti)
        paf[ti] = *(const h8*)&myps[(ti * 16 + ln) * 40 + lg * 8];

    // ---- V frags from LDS (drain the global_load_lds first; by now the
    // ~24KB issued at the top has long returned) ----
    asm volatile("s_waitcnt vmcnt(0)" ::: "memory");
    __builtin_amdgcn_sched_barrier(0);

    // B-frag: vf[tj][t] = V[p = lg*8+t][d = tj*16+ln]
    h8 vf[4];
    if constexpr (ISBF) {
        const unsigned short* vh = (const unsigned short*)myv;
#pragma unroll
        for (int tj = 0; tj < 4; ++tj)
#pragma unroll
            for (int t = 0; t < 8; ++t)
                vf[tj][t] = (_Float16)bf2f(vh[(lg * 8 + t) * 64 + tj * 16 + ln]);
    } else {
        const float* vfp = (const float*)myv;
#pragma unroll
        for (int tj = 0; tj < 4; ++tj)
#pragma unroll
            for (int t = 0; t < 8; ++t)
                vf[tj][t] = (_Float16)vfp[(lg * 8 + t) * 64 + tj * 16 + ln];
    }

    // ---- O = P * V : 2x4 tiles, store fused (plain f32; P pre-normalized) ----
    // out[b][s = j*32 + row][h*64 + d], d = tj*16+ln, row = ti*16+lg*4+reg
#pragma unroll
    for (int ti = 0; ti < 2; ++ti) {
#pragma unroll
        for (int tj = 0; tj < 4; ++tj) {
            f4 acc = {0.f, 0.f, 0.f, 0.f};
            acc = __builtin_amdgcn_mfma_f32_16x16x32_f16(paf[ti], vf[tj], acc, 0, 0, 0);
#pragma unroll
            for (int reg = 0; reg < 4; ++reg) {
                const int row = ti * 16 + lg * 4 + reg;
                outp[((size_t)b * 2048 + j * 32 + row) * 1024 + h * 64 + tj * 16 + ln] =
                    acc[reg];
            }
        }
    }
}

__global__ __launch_bounds__(256, 4)
void attn_jobs(const void* __restrict__ qp, const void* __restrict__ kp,
               const void* __restrict__ vp, float* __restrict__ outp) {
    // Per-wave P-transpose buffer (f16, stride 40: 16B-aligned rows) and
    // per-wave V staging buffer (raw bytes, row-major, filled by
    // global_load_lds). 10240 + 32768 = 43008 B -> 3 blocks/CU.
    __shared__ alignas(16) _Float16 ps[4][32 * 40];
    __shared__ alignas(16) unsigned char vbuf[4][8192];

    const int tid  = threadIdx.x;
    const int wid  = tid >> 6;
    const int lane = tid & 63;
    const int lg   = lane >> 4;
    const int ln   = lane & 15;

    const int sub = blockIdx.x * 4 + wid;   // 0..8191
    const int j = sub & 63;
    const int h = (sub >> 6) & 15;
    const int b = sub >> 10;

    // ---- input dtype probe (wave-uniform): bf16 stream has bf16-exponent at
    // bits[14:7] of every dword; f32 stream has uniform mantissa bits there.
    unsigned int w0 = ((const unsigned int*)qp)[lane];
    unsigned int e8 = (w0 >> 7) & 0xFFu;
    bool hitb = (e8 >= 96u) && (e8 <= 144u);
    const bool isbf = (__popcll(__ballot(hitb)) >= 32);

    if (isbf) run<true >(qp, kp, vp, outp, ps[wid], vbuf[wid], lane, lg, ln, b, h, j);
    else      run<false>(qp, kp, vp, outp, ps[wid], vbuf[wid], lane, lg, ln, b, h, j);
}

extern "C" void kernel_launch(void* const* d_in, const int* in_sizes, int n_in,
                              void* d_out, int out_size, void* d_ws, size_t ws_size,
                              hipStream_t stream) {
    (void)in_sizes; (void)n_in; (void)d_ws; (void)ws_size; (void)out_size;
    const void* q = d_in[0];
    const void* k = d_in[1];
    const void* v = d_in[2];
    // d_in[3] (op_mapping) / d_in[4] (triu_mask) are deterministic constants;
    // their structure is baked into the kernel.
    attn_jobs<<<2048, 256, 0, stream>>>(q, k, v, (float*)d_out);
}